// Round 6
// baseline (165.925 us; speedup 1.0000x reference)
//
#include <hip/hip_runtime.h>
#include <hip/hip_bf16.h>

#define N_NODES 2048
#define N_PAIRS 65536
#define DIM 512
#define NP 16
#define SLOTS 96   // max pairs per row (Poisson(32), observed max ~60)
#define SP 520     // LDS stride (bf16) for 512-col prod tile

typedef __attribute__((ext_vector_type(8))) short s16x8;
typedef __attribute__((ext_vector_type(8))) unsigned short u16x8;
typedef __attribute__((ext_vector_type(4))) float f32x4;

static __device__ __forceinline__ unsigned short f2bf(float x) {
    union { float f; unsigned int u; } v; v.f = x;
    unsigned int r = v.u + 0x7FFFu + ((v.u >> 16) & 1u);   // RNE
    return (unsigned short)(r >> 16);
}
static __device__ __forceinline__ float bf2f(unsigned short u) {
    union { unsigned int u; float f; } v; v.u = ((unsigned int)u) << 16;
    return v.f;
}
static __device__ __forceinline__ u16x8 pack8(float4 a, float4 b) {
    u16x8 r;
    r[0]=f2bf(a.x); r[1]=f2bf(a.y); r[2]=f2bf(a.z); r[3]=f2bf(a.w);
    r[4]=f2bf(b.x); r[5]=f2bf(b.y); r[6]=f2bf(b.z); r[7]=f2bf(b.w);
    return r;
}

// ---------------------------------------------------------------------------
// Kernel 1: fused dual GEMM via bf16 MFMA (unchanged R3 anchor).
// ---------------------------------------------------------------------------
#define GBM 64
#define GBN 64
#define GBK 32
#define GSA 40

__global__ __launch_bounds__(256) void gemm_so(
    const float* __restrict__ A, const float* __restrict__ Ws, const float* __restrict__ bsv,
    const float* __restrict__ Wo, const float* __restrict__ bov,
    unsigned short* __restrict__ Sb, unsigned short* __restrict__ Ob)
{
    __shared__ unsigned short As[GBM*GSA];
    __shared__ unsigned short Bs[GBN*GSA];
    const int tid = threadIdx.x;
    const int m0 = blockIdx.y*GBM, n0 = blockIdx.x*GBN;
    const int ar = tid>>2, ac = (tid&3)*8;
    const float* Arow = A + (size_t)(m0+ar)*DIM + ac;
    const int nrow = n0 + ar;
    const float* Wrow = (nrow < DIM ? Ws + (size_t)nrow*DIM : Wo + (size_t)(nrow-DIM)*DIM) + ac;
    float4 a_r[2], b_r[2];
    a_r[0] = *(const float4*)(Arow);   a_r[1] = *(const float4*)(Arow+4);
    b_r[0] = *(const float4*)(Wrow);   b_r[1] = *(const float4*)(Wrow+4);

    const int lane = tid&63, wid = tid>>6;
    const int wm = (wid>>1)*32, wn = (wid&1)*32;
    const int fr = lane&15, ks8 = (lane>>4)*8;
    f32x4 acc[2][2] = {};
    for (int k0=0; k0<DIM; k0+=GBK) {
        *(u16x8*)&As[ar*GSA+ac] = pack8(a_r[0],a_r[1]);
        *(u16x8*)&Bs[ar*GSA+ac] = pack8(b_r[0],b_r[1]);
        __syncthreads();
        if (k0+GBK < DIM) {
            a_r[0] = *(const float4*)(Arow + k0+GBK);   a_r[1] = *(const float4*)(Arow + k0+GBK + 4);
            b_r[0] = *(const float4*)(Wrow + k0+GBK);   b_r[1] = *(const float4*)(Wrow + k0+GBK + 4);
        }
        s16x8 af[2], bfr[2];
        #pragma unroll
        for (int mi=0;mi<2;++mi) af[mi]  = *(const s16x8*)&As[(wm+mi*16+fr)*GSA + ks8];
        #pragma unroll
        for (int ni=0;ni<2;++ni) bfr[ni] = *(const s16x8*)&Bs[(wn+ni*16+fr)*GSA + ks8];
        #pragma unroll
        for (int mi=0;mi<2;++mi)
            #pragma unroll
            for (int ni=0;ni<2;++ni)
                acc[mi][ni] = __builtin_amdgcn_mfma_f32_16x16x32_bf16(af[mi], bfr[ni], acc[mi][ni], 0,0,0);
        __syncthreads();
    }
    const int rg = lane>>4;
    #pragma unroll
    for (int ni=0;ni<2;++ni) {
        const int n = n0 + wn + ni*16 + fr;
        const float bias = (n < DIM) ? bsv[n] : bov[n-DIM];
        unsigned short* dst = (n < DIM) ? (Sb + n) : (Ob + (n - DIM));
        #pragma unroll
        for (int mi=0;mi<2;++mi) {
            #pragma unroll
            for (int q=0;q<4;++q) {
                const int m = m0 + wm + mi*16 + rg*4 + q;
                dst[(size_t)m*DIM] = f2bf(acc[mi][ni][q] + bias);
            }
        }
    }
}

// ---------------------------------------------------------------------------
// Kernel 2: route pair-ids into per-row slot lists (replaces CSR build).
// ---------------------------------------------------------------------------
__global__ __launch_bounds__(256) void route_k(
    const int* __restrict__ idx, int* __restrict__ rowcnt, int* __restrict__ rowj)
{
    const int e = blockIdx.x * 256 + threadIdx.x;
    const int i = idx[2*e];
    const int pos = atomicAdd(&rowcnt[i], 1);
    if (pos < SLOTS) rowj[i*SLOTS + pos] = e;
}

// ---------------------------------------------------------------------------
// Kernel 3: fused pair-projection + softmax, one block per output row.
// Stage slot list -> R3-style wave-batched MFMA projection (16 slots/wave,
// LDS prod tile, w fragments in registers; s_r loaded once) -> logits in LDS
// -> dedup -> stats -> probs + col->slot map -> single-pass dense write.
// ---------------------------------------------------------------------------
__global__ __launch_bounds__(256) void fused_sm(
    const unsigned short* __restrict__ Sb, const unsigned short* __restrict__ Ob,
    const float* __restrict__ U, const int* __restrict__ idx,
    const float* __restrict__ w_w, const float* __restrict__ w_b,
    const int* __restrict__ rowcnt, const int* __restrict__ rowj,
    float* __restrict__ out)
{
    __shared__ __align__(16) unsigned short P[4*16*SP];   // 66560 B
    __shared__ __align__(16) float vals[(SLOTS+2)*NP];    // 6.1 KB
    __shared__ int elds[SLOTS];
    __shared__ int jcol[SLOTS];
    __shared__ unsigned char deadf[SLOTS];
    __shared__ unsigned char cmap[N_NODES];               // 2 KB
    __shared__ float red[16][17];
    __shared__ float mPv[NP], invZv[NP];
    __shared__ int ndv;

    const int r = blockIdx.x;
    const int t = threadIdx.x;
    const int lane = t & 63, wid = t >> 6;
    const int fr = lane & 15, ks8 = (lane >> 4) * 8;

    // w_w fragments in registers (64 VGPR), bias
    s16x8 wreg[16];
    #pragma unroll
    for (int st = 0; st < 16; ++st) {
        const float4* wp = (const float4*)(w_w + (size_t)fr*DIM + st*32 + ks8);
        u16x8 tm = pack8(wp[0], wp[1]);
        wreg[st] = *(s16x8*)&tm;
    }
    const float wbv = w_b[fr];

    int c = rowcnt[r];
    if (c > SLOTS) c = SLOTS;

    if (t == 0) ndv = 0;
    for (int n = t; n < N_NODES; n += 256) cmap[n] = (unsigned char)SLOTS;  // bg
    for (int a = t; a < c; a += 256) {
        const int e = rowj[r*SLOTS + a];
        elds[a] = e;
        jcol[a] = idx[2*e + 1];
        deadf[a] = 0;
    }
    __syncthreads();

    // s_r chunk for this lane (same for every pair in the row)
    const u16x8 sv = *(const u16x8*)(Sb + (size_t)r*DIM + lane*8);

    // projection: wave handles 16 slots per batch
    unsigned short* Pw = &P[wid*16*SP];
    for (int a0 = wid*16; a0 < c; a0 += 64) {
        const int nb = (c - a0 < 16) ? (c - a0) : 16;
        for (int s8 = 0; s8 < nb; ++s8) {
            const int e = elds[a0 + s8];
            const int j = jcol[a0 + s8];
            const u16x8 ov = *(const u16x8*)(Ob + (size_t)j*DIM + lane*8);
            const float4* up = (const float4*)(U + (size_t)e*DIM + lane*8);
            const float4 u0 = up[0], u1 = up[1];
            float4 p0, p1;
            p0.x = bf2f(sv[0])*bf2f(ov[0])*u0.x;
            p0.y = bf2f(sv[1])*bf2f(ov[1])*u0.y;
            p0.z = bf2f(sv[2])*bf2f(ov[2])*u0.z;
            p0.w = bf2f(sv[3])*bf2f(ov[3])*u0.w;
            p1.x = bf2f(sv[4])*bf2f(ov[4])*u1.x;
            p1.y = bf2f(sv[5])*bf2f(ov[5])*u1.y;
            p1.z = bf2f(sv[6])*bf2f(ov[6])*u1.z;
            p1.w = bf2f(sv[7])*bf2f(ov[7])*u1.w;
            *(u16x8*)&Pw[s8*SP + lane*8] = pack8(p0, p1);
        }
        f32x4 acc = {0.f, 0.f, 0.f, 0.f};
        #pragma unroll
        for (int st = 0; st < 16; ++st) {
            s16x8 af = *(const s16x8*)&Pw[fr*SP + st*32 + ks8];
            acc = __builtin_amdgcn_mfma_f32_16x16x32_bf16(af, wreg[st], acc, 0,0,0);
        }
        const int rg = lane >> 4;
        #pragma unroll
        for (int q = 0; q < 4; ++q) {
            const int sa = rg*4 + q;
            if (sa < nb) vals[(a0 + sa)*NP + fr] = acc[q] + wbv;
        }
    }
    __syncthreads();

    // merge duplicate columns into first occurrence
    for (int a = t; a < c; a += 256) {
        const int j = jcol[a];
        int first = a;
        for (int b = 0; b < a; ++b) if (jcol[b] == j) { first = b; break; }
        if (first != a) {
            deadf[a] = 1;
            #pragma unroll
            for (int p = 0; p < NP; ++p) atomicAdd(&vals[first*NP+p], vals[a*NP+p]);
        }
    }
    __syncthreads();
    for (int a = t; a < c; a += 256)
        if (!deadf[a] && jcol[a] != r) atomicAdd(&ndv, 1);
    __syncthreads();

    // stats: 16 chunks x 16 p
    const int p = t & 15, ch = t >> 4;
    float pm = 0.f;   // background logit 0 always present
    for (int a = ch; a < c; a += 16)
        if (!deadf[a] && jcol[a] != r) pm = fmaxf(pm, vals[a*NP+p]);
    red[ch][p] = pm;
    __syncthreads();
    if (t < NP) {
        float m = 0.f;
        #pragma unroll
        for (int k = 0; k < 16; ++k) m = fmaxf(m, red[k][t]);
        mPv[t] = m;
    }
    __syncthreads();
    {
        const float m = mPv[p];
        float ps = 0.f;
        for (int a = ch; a < c; a += 16)
            if (!deadf[a] && jcol[a] != r) ps += __expf(vals[a*NP+p] - m);
        red[ch][p] = ps;
    }
    __syncthreads();
    if (t < NP) {
        float zs = 0.f;
        #pragma unroll
        for (int k = 0; k < 16; ++k) zs += red[k][t];
        const float m = mPv[t];
        const float eb = __expf(-m);
        const float Z = zs + (float)(N_NODES - 1 - ndv) * eb;
        const float iz = 1.0f / Z;
        invZv[t] = iz;
        vals[SLOTS*NP + t] = eb * iz;       // background prob row
        vals[(SLOTS+1)*NP + t] = 0.f;       // zero row (diagonal)
    }
    __syncthreads();

    // probs in place + live column map
    for (int a = t; a < c; a += 256) {
        if (!deadf[a] && jcol[a] != r) {
            #pragma unroll
            for (int p2 = 0; p2 < NP; ++p2)
                vals[a*NP+p2] = __expf(vals[a*NP+p2] - mPv[p2]) * invZv[p2];
            cmap[jcol[a]] = (unsigned char)a;
        }
    }
    __syncthreads();
    if (t == 0) cmap[r] = (unsigned char)(SLOTS+1);
    __syncthreads();

    // single-pass dense write: 8192 float4, 32 per thread
    float4* orow = (float4*)(out + (size_t)r * N_NODES * NP);
    const float4* v4 = (const float4*)vals;
    #pragma unroll 8
    for (int n = 0; n < 32; ++n) {
        const int i4 = t + 256*n;
        const int col = i4 >> 2, q = i4 & 3;
        orow[i4] = v4[(int)cmap[col]*4 + q];
    }
}

// ---------------------------------------------------------------------------
extern "C" void kernel_launch(void* const* d_in, const int* in_sizes, int n_in,
                              void* d_out, int out_size, void* d_ws, size_t ws_size,
                              hipStream_t stream)
{
    (void)in_sizes; (void)n_in; (void)out_size; (void)ws_size;
    const float* obj  = (const float*)d_in[0];
    const float* uni  = (const float*)d_in[1];
    const int*   idx  = (const int*)  d_in[2];
    const float* ws_w = (const float*)d_in[3];
    const float* ws_b = (const float*)d_in[4];
    const float* wo_w = (const float*)d_in[5];
    const float* wo_b = (const float*)d_in[6];
    const float* w_w  = (const float*)d_in[7];
    const float* w_b  = (const float*)d_in[8];
    float* out = (float*)d_out;

    unsigned short* Sb = (unsigned short*)d_ws;                 // 2 MB bf16
    unsigned short* Ob = Sb + (size_t)N_NODES * DIM;            // 2 MB bf16
    int* rowj   = (int*)(Ob + (size_t)N_NODES * DIM);           // 2048*96 ints = 768 KB
    int* rowcnt = rowj + (size_t)N_NODES * SLOTS;               // 8 KB

    hipMemsetAsync(rowcnt, 0, N_NODES * sizeof(int), stream);
    route_k<<<N_PAIRS/256, 256, 0, stream>>>(idx, rowcnt, rowj);
    gemm_so<<<dim3(1024/GBN, N_NODES/GBM), 256, 0, stream>>>(obj, ws_w, ws_b, wo_w, wo_b, Sb, Ob);
    fused_sm<<<N_NODES, 256, 0, stream>>>(Sb, Ob, uni, idx, w_w, w_b, rowcnt, rowj, out);
}

// Round 7
// 138.201 us; speedup vs baseline: 1.2006x; 1.2006x over previous
//
#include <hip/hip_runtime.h>
#include <hip/hip_bf16.h>

#define N_NODES 2048
#define N_PAIRS 65536
#define DIM 512
#define NP 16
#define SLOTS 96   // max pairs per row (Poisson(32), observed max ~60)
#define SP 520     // LDS stride (bf16) for 512-col prod tile

typedef __attribute__((ext_vector_type(8))) short s16x8;
typedef __attribute__((ext_vector_type(8))) unsigned short u16x8;
typedef __attribute__((ext_vector_type(4))) float f32x4;

static __device__ __forceinline__ unsigned short f2bf(float x) {
    union { float f; unsigned int u; } v; v.f = x;
    unsigned int r = v.u + 0x7FFFu + ((v.u >> 16) & 1u);   // RNE
    return (unsigned short)(r >> 16);
}
static __device__ __forceinline__ float bf2f(unsigned short u) {
    union { unsigned int u; float f; } v; v.u = ((unsigned int)u) << 16;
    return v.f;
}
static __device__ __forceinline__ u16x8 pack8(float4 a, float4 b) {
    u16x8 r;
    r[0]=f2bf(a.x); r[1]=f2bf(a.y); r[2]=f2bf(a.z); r[3]=f2bf(a.w);
    r[4]=f2bf(b.x); r[5]=f2bf(b.y); r[6]=f2bf(b.z); r[7]=f2bf(b.w);
    return r;
}

// ---------------------------------------------------------------------------
// Kernel 1: fused dual GEMM via bf16 MFMA (unchanged R3 anchor).
// ---------------------------------------------------------------------------
#define GBM 64
#define GBN 64
#define GBK 32
#define GSA 40

__global__ __launch_bounds__(256) void gemm_so(
    const float* __restrict__ A, const float* __restrict__ Ws, const float* __restrict__ bsv,
    const float* __restrict__ Wo, const float* __restrict__ bov,
    unsigned short* __restrict__ Sb, unsigned short* __restrict__ Ob)
{
    __shared__ unsigned short As[GBM*GSA];
    __shared__ unsigned short Bs[GBN*GSA];
    const int tid = threadIdx.x;
    const int m0 = blockIdx.y*GBM, n0 = blockIdx.x*GBN;
    const int ar = tid>>2, ac = (tid&3)*8;
    const float* Arow = A + (size_t)(m0+ar)*DIM + ac;
    const int nrow = n0 + ar;
    const float* Wrow = (nrow < DIM ? Ws + (size_t)nrow*DIM : Wo + (size_t)(nrow-DIM)*DIM) + ac;
    float4 a_r[2], b_r[2];
    a_r[0] = *(const float4*)(Arow);   a_r[1] = *(const float4*)(Arow+4);
    b_r[0] = *(const float4*)(Wrow);   b_r[1] = *(const float4*)(Wrow+4);

    const int lane = tid&63, wid = tid>>6;
    const int wm = (wid>>1)*32, wn = (wid&1)*32;
    const int fr = lane&15, ks8 = (lane>>4)*8;
    f32x4 acc[2][2] = {};
    for (int k0=0; k0<DIM; k0+=GBK) {
        *(u16x8*)&As[ar*GSA+ac] = pack8(a_r[0],a_r[1]);
        *(u16x8*)&Bs[ar*GSA+ac] = pack8(b_r[0],b_r[1]);
        __syncthreads();
        if (k0+GBK < DIM) {
            a_r[0] = *(const float4*)(Arow + k0+GBK);   a_r[1] = *(const float4*)(Arow + k0+GBK + 4);
            b_r[0] = *(const float4*)(Wrow + k0+GBK);   b_r[1] = *(const float4*)(Wrow + k0+GBK + 4);
        }
        s16x8 af[2], bfr[2];
        #pragma unroll
        for (int mi=0;mi<2;++mi) af[mi]  = *(const s16x8*)&As[(wm+mi*16+fr)*GSA + ks8];
        #pragma unroll
        for (int ni=0;ni<2;++ni) bfr[ni] = *(const s16x8*)&Bs[(wn+ni*16+fr)*GSA + ks8];
        #pragma unroll
        for (int mi=0;mi<2;++mi)
            #pragma unroll
            for (int ni=0;ni<2;++ni)
                acc[mi][ni] = __builtin_amdgcn_mfma_f32_16x16x32_bf16(af[mi], bfr[ni], acc[mi][ni], 0,0,0);
        __syncthreads();
    }
    const int rg = lane>>4;
    #pragma unroll
    for (int ni=0;ni<2;++ni) {
        const int n = n0 + wn + ni*16 + fr;
        const float bias = (n < DIM) ? bsv[n] : bov[n-DIM];
        unsigned short* dst = (n < DIM) ? (Sb + n) : (Ob + (n - DIM));
        #pragma unroll
        for (int mi=0;mi<2;++mi) {
            #pragma unroll
            for (int q=0;q<4;++q) {
                const int m = m0 + wm + mi*16 + rg*4 + q;
                dst[(size_t)m*DIM] = f2bf(acc[mi][ni][q] + bias);
            }
        }
    }
}

// ---------------------------------------------------------------------------
// Kernel 2: pair projection via MFMA + direct per-row slot scatter.
// CHANGE vs 130.9µs anchor: 8-pair batches (was 16) -> LDS 66.5KB -> 33.3KB
// -> 4 blocks/CU (was 2) -> 4 waves/SIMD for gather latency hiding.
// MFMA A rows 8..15 read duplicated rows via (fr&7); scatter masked to pr<8.
// ---------------------------------------------------------------------------
__global__ __launch_bounds__(256) void pairproj_k(
    const unsigned short* __restrict__ Sb, const unsigned short* __restrict__ Ob,
    const float* __restrict__ U, const int* __restrict__ idx,
    const float* __restrict__ w_w, const float* __restrict__ w_b,
    int* __restrict__ rowcnt, int* __restrict__ rowj, float* __restrict__ rowv)
{
    __shared__ unsigned short P[4*8*SP];   // 33280 B -> 4 blocks/CU
    const int tid = threadIdx.x;
    const int lane = tid&63, wid = tid>>6;
    const int fr = lane&15, ks8 = (lane>>4)*8;
    s16x8 wreg[16];
    #pragma unroll
    for (int st=0;st<16;++st) {
        const float4* wp = (const float4*)(w_w + (size_t)fr*DIM + st*32 + ks8);
        u16x8 t = pack8(wp[0], wp[1]);
        wreg[st] = *(s16x8*)&t;
    }
    const float wbv = w_b[fr];
    unsigned short* Pw = &P[wid*8*SP];
    const int eb = blockIdx.x*128 + wid*32;
    for (int it=0; it<4; ++it) {
        const int e0 = eb + it*8;
        #pragma unroll 4
        for (int s8=0; s8<8; ++s8) {
            const int e = e0 + s8;
            const int i = idx[2*e], j = idx[2*e+1];
            u16x8 sv = *(const u16x8*)(Sb + (size_t)i*DIM + lane*8);
            u16x8 ov = *(const u16x8*)(Ob + (size_t)j*DIM + lane*8);
            const float4* up = (const float4*)(U + (size_t)e*DIM + lane*8);
            float4 u0 = up[0], u1 = up[1];
            float4 p0, p1;
            p0.x = bf2f(sv[0])*bf2f(ov[0])*u0.x;
            p0.y = bf2f(sv[1])*bf2f(ov[1])*u0.y;
            p0.z = bf2f(sv[2])*bf2f(ov[2])*u0.z;
            p0.w = bf2f(sv[3])*bf2f(ov[3])*u0.w;
            p1.x = bf2f(sv[4])*bf2f(ov[4])*u1.x;
            p1.y = bf2f(sv[5])*bf2f(ov[5])*u1.y;
            p1.z = bf2f(sv[6])*bf2f(ov[6])*u1.z;
            p1.w = bf2f(sv[7])*bf2f(ov[7])*u1.w;
            *(u16x8*)&Pw[s8*SP + lane*8] = pack8(p0, p1);
        }
        f32x4 acc = {0.f,0.f,0.f,0.f};
        #pragma unroll
        for (int st=0;st<16;++st) {
            s16x8 af = *(const s16x8*)&Pw[(fr&7)*SP + st*32 + ks8];
            acc = __builtin_amdgcn_mfma_f32_16x16x32_bf16(af, wreg[st], acc, 0,0,0);
        }
        // slot allocation: lanes 0..7 own pairs e0+lane
        int iv = 0, posv = 0;
        if (lane < 8) {
            const int e = e0 + lane;
            iv = idx[2*e];
            const int jv = idx[2*e + 1];
            posv = atomicAdd(&rowcnt[iv], 1);
            if (posv < SLOTS) rowj[iv*SLOTS + posv] = jv;
        }
        const int rg = lane>>4;
        #pragma unroll
        for (int q=0;q<4;++q) {
            const int pr = rg*4 + q;
            if (pr < 8) {
                const int ip = __shfl(iv, pr, 64);
                const int pp = __shfl(posv, pr, 64);
                if (pp < SLOTS)
                    rowv[((size_t)ip*SLOTS + pp)*NP + fr] = acc[q] + wbv;
            }
        }
    }
}

// ---------------------------------------------------------------------------
// Kernel 3: per-row sparse softmax (unchanged R3 anchor: two-pass write).
// ---------------------------------------------------------------------------
__global__ __launch_bounds__(256) void softmax_k(
    const int* __restrict__ rowcnt, const int* __restrict__ rowj,
    const float* __restrict__ rowv, float* __restrict__ out)
{
    __shared__ __align__(16) float vals[SLOTS][NP];   // 6 KB
    __shared__ int jcol[SLOTS];
    __shared__ unsigned char dead[SLOTS];
    __shared__ float red[16][17];
    __shared__ float mP[NP], invZ[NP], bg[NP];
    __shared__ int ndistinct;
    const int i = blockIdx.x;
    const int t = threadIdx.x;
    int c = rowcnt[i];
    if (c > SLOTS) c = SLOTS;

    if (t == 0) ndistinct = 0;
    for (int a = t; a < c; a += 256) {
        jcol[a] = rowj[i*SLOTS + a];
        dead[a] = 0;
        const float4* src = (const float4*)(rowv + ((size_t)i*SLOTS + a)*NP);
        float4* dst = (float4*)vals[a];
        dst[0] = src[0]; dst[1] = src[1]; dst[2] = src[2]; dst[3] = src[3];
    }
    __syncthreads();

    // merge duplicate columns into first occurrence
    for (int a = t; a < c; a += 256) {
        int j = jcol[a];
        int first = a;
        for (int b = 0; b < a; ++b) if (jcol[b] == j) { first = b; break; }
        if (first != a) {
            dead[a] = 1;
            #pragma unroll
            for (int p = 0; p < NP; ++p) atomicAdd(&vals[first][p], vals[a][p]);
        }
    }
    __syncthreads();
    for (int a = t; a < c; a += 256)
        if (!dead[a] && jcol[a] != i) atomicAdd(&ndistinct, 1);
    __syncthreads();

    // stats: 16 chunks x 16 p
    const int p = t & 15, ch = t >> 4;
    float pm = 0.f;   // background logit 0 always present
    for (int a = ch; a < c; a += 16)
        if (!dead[a] && jcol[a] != i) pm = fmaxf(pm, vals[a][p]);
    red[ch][p] = pm;
    __syncthreads();
    if (t < NP) {
        float m = 0.f;
        #pragma unroll
        for (int k = 0; k < 16; ++k) m = fmaxf(m, red[k][t]);
        mP[t] = m;
    }
    __syncthreads();
    {
        const float m = mP[p];
        float ps = 0.f;
        for (int a = ch; a < c; a += 16)
            if (!dead[a] && jcol[a] != i) ps += __expf(vals[a][p] - m);
        red[ch][p] = ps;
    }
    __syncthreads();
    if (t < NP) {
        float zs = 0.f;
        #pragma unroll
        for (int k = 0; k < 16; ++k) zs += red[k][t];
        const float m = mP[t];
        const float eb = __expf(-m);
        const float nbg = (float)(N_NODES - 1 - ndistinct);
        const float Z = zs + nbg * eb;
        const float iz = 1.0f / Z;
        invZ[t] = iz; bg[t] = eb * iz;
    }
    __syncthreads();

    // dense background write: 2048*16 floats = 8192 float4
    const size_t rowbase = (size_t)i * N_NODES * NP;
    {
        const int g = t & 3;
        float4 b4 = make_float4(bg[g*4+0], bg[g*4+1], bg[g*4+2], bg[g*4+3]);
        float4* orow = (float4*)(out + rowbase);
        #pragma unroll 8
        for (int n = 0; n < 32; ++n) orow[t + 256 * n] = b4;
    }
    __syncthreads();

    // fixups: sparse columns and diagonal
    for (int a = t; a < c; a += 256) {
        if (dead[a]) continue;
        const int j = jcol[a];
        float4* dst = (float4*)(out + rowbase + (size_t)j * NP);
        if (j == i) {
            float4 z = make_float4(0.f, 0.f, 0.f, 0.f);
            dst[0] = z; dst[1] = z; dst[2] = z; dst[3] = z;
        } else {
            #pragma unroll
            for (int q = 0; q < 4; ++q) {
                float4 v;
                v.x = __expf(vals[a][4*q+0] - mP[4*q+0]) * invZ[4*q+0];
                v.y = __expf(vals[a][4*q+1] - mP[4*q+1]) * invZ[4*q+1];
                v.z = __expf(vals[a][4*q+2] - mP[4*q+2]) * invZ[4*q+2];
                v.w = __expf(vals[a][4*q+3] - mP[4*q+3]) * invZ[4*q+3];
                dst[q] = v;
            }
        }
    }
    if (t == 0) {
        float4 z = make_float4(0.f, 0.f, 0.f, 0.f);
        float4* dst = (float4*)(out + rowbase + (size_t)i * NP);
        dst[0] = z; dst[1] = z; dst[2] = z; dst[3] = z;
    }
}

// ---------------------------------------------------------------------------
extern "C" void kernel_launch(void* const* d_in, const int* in_sizes, int n_in,
                              void* d_out, int out_size, void* d_ws, size_t ws_size,
                              hipStream_t stream)
{
    (void)in_sizes; (void)n_in; (void)out_size; (void)ws_size;
    const float* obj  = (const float*)d_in[0];
    const float* uni  = (const float*)d_in[1];
    const int*   idx  = (const int*)  d_in[2];
    const float* ws_w = (const float*)d_in[3];
    const float* ws_b = (const float*)d_in[4];
    const float* wo_w = (const float*)d_in[5];
    const float* wo_b = (const float*)d_in[6];
    const float* w_w  = (const float*)d_in[7];
    const float* w_b  = (const float*)d_in[8];
    float* out = (float*)d_out;

    unsigned short* Sb = (unsigned short*)d_ws;                     // 2 MB bf16
    unsigned short* Ob = Sb + (size_t)N_NODES * DIM;                // 2 MB bf16
    float* rowv  = (float*)(Ob + (size_t)N_NODES * DIM);            // 12.6 MB
    int* rowj    = (int*)(rowv + (size_t)N_NODES * SLOTS * NP);     // 768 KB
    int* rowcnt  = rowj + (size_t)N_NODES * SLOTS;                  // 8 KB

    hipMemsetAsync(rowcnt, 0, N_NODES * sizeof(int), stream);
    gemm_so<<<dim3(1024/GBN, N_NODES/GBM), 256, 0, stream>>>(obj, ws_w, ws_b, wo_w, wo_b, Sb, Ob);
    pairproj_k<<<N_PAIRS/128, 256, 0, stream>>>(Sb, Ob, uni, idx, w_w, w_b, rowcnt, rowj, rowv);
    softmax_k<<<N_NODES, 256, 0, stream>>>(rowcnt, rowj, rowv, out);
}

// Round 8
// 122.781 us; speedup vs baseline: 1.3514x; 1.1256x over previous
//
#include <hip/hip_runtime.h>
#include <hip/hip_bf16.h>

#define N_NODES 2048
#define N_PAIRS 65536
#define DIM 512
#define NP 16
#define SLOTS 96   // max pairs per row (Poisson(32), observed max ~60)
#define SP 520     // LDS stride (bf16) for 512-col prod tile

typedef __attribute__((ext_vector_type(8))) short s16x8;
typedef __attribute__((ext_vector_type(8))) unsigned short u16x8;
typedef __attribute__((ext_vector_type(4))) float f32x4;

static __device__ __forceinline__ unsigned short f2bf(float x) {
    union { float f; unsigned int u; } v; v.f = x;
    unsigned int r = v.u + 0x7FFFu + ((v.u >> 16) & 1u);   // RNE
    return (unsigned short)(r >> 16);
}
static __device__ __forceinline__ float bf2f(unsigned short u) {
    union { unsigned int u; float f; } v; v.u = ((unsigned int)u) << 16;
    return v.f;
}
static __device__ __forceinline__ u16x8 pack8(float4 a, float4 b) {
    u16x8 r;
    r[0]=f2bf(a.x); r[1]=f2bf(a.y); r[2]=f2bf(a.z); r[3]=f2bf(a.w);
    r[4]=f2bf(b.x); r[5]=f2bf(b.y); r[6]=f2bf(b.z); r[7]=f2bf(b.w);
    return r;
}
static __device__ __forceinline__ void store_nt4(float* p, float a, float b, float c, float d) {
    f32x4 v = {a, b, c, d};
    __builtin_nontemporal_store(v, (f32x4*)p);
}

// ---------------------------------------------------------------------------
// Kernel 1: fused dual GEMM via bf16 MFMA (R3 anchor) + rowcnt zeroing
// folded in (replaces the memset dispatch; pairproj runs strictly after).
// ---------------------------------------------------------------------------
#define GBM 64
#define GBN 64
#define GBK 32
#define GSA 40

__global__ __launch_bounds__(256) void gemm_so(
    const float* __restrict__ A, const float* __restrict__ Ws, const float* __restrict__ bsv,
    const float* __restrict__ Wo, const float* __restrict__ bov,
    unsigned short* __restrict__ Sb, unsigned short* __restrict__ Ob,
    int* __restrict__ rowcnt)
{
    __shared__ unsigned short As[GBM*GSA];
    __shared__ unsigned short Bs[GBN*GSA];
    const int tid = threadIdx.x;
    // fold: zero rowcnt (8 blocks x 256 ints)
    {
        const int bid = blockIdx.y * gridDim.x + blockIdx.x;
        if (bid < 8) rowcnt[bid*256 + tid] = 0;
    }
    const int m0 = blockIdx.y*GBM, n0 = blockIdx.x*GBN;
    const int ar = tid>>2, ac = (tid&3)*8;
    const float* Arow = A + (size_t)(m0+ar)*DIM + ac;
    const int nrow = n0 + ar;
    const float* Wrow = (nrow < DIM ? Ws + (size_t)nrow*DIM : Wo + (size_t)(nrow-DIM)*DIM) + ac;
    float4 a_r[2], b_r[2];
    a_r[0] = *(const float4*)(Arow);   a_r[1] = *(const float4*)(Arow+4);
    b_r[0] = *(const float4*)(Wrow);   b_r[1] = *(const float4*)(Wrow+4);

    const int lane = tid&63, wid = tid>>6;
    const int wm = (wid>>1)*32, wn = (wid&1)*32;
    const int fr = lane&15, ks8 = (lane>>4)*8;
    f32x4 acc[2][2] = {};
    for (int k0=0; k0<DIM; k0+=GBK) {
        *(u16x8*)&As[ar*GSA+ac] = pack8(a_r[0],a_r[1]);
        *(u16x8*)&Bs[ar*GSA+ac] = pack8(b_r[0],b_r[1]);
        __syncthreads();
        if (k0+GBK < DIM) {
            a_r[0] = *(const float4*)(Arow + k0+GBK);   a_r[1] = *(const float4*)(Arow + k0+GBK + 4);
            b_r[0] = *(const float4*)(Wrow + k0+GBK);   b_r[1] = *(const float4*)(Wrow + k0+GBK + 4);
        }
        s16x8 af[2], bfr[2];
        #pragma unroll
        for (int mi=0;mi<2;++mi) af[mi]  = *(const s16x8*)&As[(wm+mi*16+fr)*GSA + ks8];
        #pragma unroll
        for (int ni=0;ni<2;++ni) bfr[ni] = *(const s16x8*)&Bs[(wn+ni*16+fr)*GSA + ks8];
        #pragma unroll
        for (int mi=0;mi<2;++mi)
            #pragma unroll
            for (int ni=0;ni<2;++ni)
                acc[mi][ni] = __builtin_amdgcn_mfma_f32_16x16x32_bf16(af[mi], bfr[ni], acc[mi][ni], 0,0,0);
        __syncthreads();
    }
    const int rg = lane>>4;
    #pragma unroll
    for (int ni=0;ni<2;++ni) {
        const int n = n0 + wn + ni*16 + fr;
        const float bias = (n < DIM) ? bsv[n] : bov[n-DIM];
        unsigned short* dst = (n < DIM) ? (Sb + n) : (Ob + (n - DIM));
        #pragma unroll
        for (int mi=0;mi<2;++mi) {
            #pragma unroll
            for (int q=0;q<4;++q) {
                const int m = m0 + wm + mi*16 + rg*4 + q;
                dst[(size_t)m*DIM] = f2bf(acc[mi][ni][q] + bias);
            }
        }
    }
}

// ---------------------------------------------------------------------------
// Kernel 2: pair projection via MFMA + direct per-row slot scatter
// (byte-identical to the 130.9 µs R3 anchor).
// ---------------------------------------------------------------------------
__global__ __launch_bounds__(256) void pairproj_k(
    const unsigned short* __restrict__ Sb, const unsigned short* __restrict__ Ob,
    const float* __restrict__ U, const int* __restrict__ idx,
    const float* __restrict__ w_w, const float* __restrict__ w_b,
    int* __restrict__ rowcnt, int* __restrict__ rowj, float* __restrict__ rowv)
{
    __shared__ unsigned short P[4*16*SP];   // 66.5 KB
    const int tid = threadIdx.x;
    const int lane = tid&63, wid = tid>>6;
    const int fr = lane&15, ks8 = (lane>>4)*8;
    s16x8 wreg[16];
    #pragma unroll
    for (int st=0;st<16;++st) {
        const float4* wp = (const float4*)(w_w + (size_t)fr*DIM + st*32 + ks8);
        u16x8 t = pack8(wp[0], wp[1]);
        wreg[st] = *(s16x8*)&t;
    }
    const float wbv = w_b[fr];
    unsigned short* Pw = &P[wid*16*SP];
    const int eb = blockIdx.x*128 + wid*32;
    for (int it=0; it<2; ++it) {
        const int e0 = eb + it*16;
        #pragma unroll 4
        for (int s8=0; s8<16; ++s8) {
            const int e = e0 + s8;
            const int i = idx[2*e], j = idx[2*e+1];
            u16x8 sv = *(const u16x8*)(Sb + (size_t)i*DIM + lane*8);
            u16x8 ov = *(const u16x8*)(Ob + (size_t)j*DIM + lane*8);
            const float4* up = (const float4*)(U + (size_t)e*DIM + lane*8);
            float4 u0 = up[0], u1 = up[1];
            float4 p0, p1;
            p0.x = bf2f(sv[0])*bf2f(ov[0])*u0.x;
            p0.y = bf2f(sv[1])*bf2f(ov[1])*u0.y;
            p0.z = bf2f(sv[2])*bf2f(ov[2])*u0.z;
            p0.w = bf2f(sv[3])*bf2f(ov[3])*u0.w;
            p1.x = bf2f(sv[4])*bf2f(ov[4])*u1.x;
            p1.y = bf2f(sv[5])*bf2f(ov[5])*u1.y;
            p1.z = bf2f(sv[6])*bf2f(ov[6])*u1.z;
            p1.w = bf2f(sv[7])*bf2f(ov[7])*u1.w;
            *(u16x8*)&Pw[s8*SP + lane*8] = pack8(p0, p1);
        }
        f32x4 acc = {0.f,0.f,0.f,0.f};
        #pragma unroll
        for (int st=0;st<16;++st) {
            s16x8 af = *(const s16x8*)&Pw[fr*SP + st*32 + ks8];
            acc = __builtin_amdgcn_mfma_f32_16x16x32_bf16(af, wreg[st], acc, 0,0,0);
        }
        int iv = 0, posv = 0;
        if (lane < 16) {
            const int e = e0 + lane;
            iv = idx[2*e];
            const int jv = idx[2*e + 1];
            posv = atomicAdd(&rowcnt[iv], 1);
            if (posv < SLOTS) rowj[iv*SLOTS + posv] = jv;
        }
        const int rg = lane>>4;
        #pragma unroll
        for (int q=0;q<4;++q) {
            const int pr = rg*4 + q;
            const int ip = __shfl(iv, pr, 64);
            const int pp = __shfl(posv, pr, 64);
            if (pp < SLOTS)
                rowv[((size_t)ip*SLOTS + pp)*NP + fr] = acc[q] + wbv;
        }
    }
}

// ---------------------------------------------------------------------------
// Kernel 3: per-row sparse softmax (R3 anchor, out writes -> non-temporal).
// ---------------------------------------------------------------------------
__global__ __launch_bounds__(256) void softmax_k(
    const int* __restrict__ rowcnt, const int* __restrict__ rowj,
    const float* __restrict__ rowv, float* __restrict__ out)
{
    __shared__ __align__(16) float vals[SLOTS][NP];   // 6 KB
    __shared__ int jcol[SLOTS];
    __shared__ unsigned char dead[SLOTS];
    __shared__ float red[16][17];
    __shared__ float mP[NP], invZ[NP], bg[NP];
    __shared__ int ndistinct;
    const int i = blockIdx.x;
    const int t = threadIdx.x;
    int c = rowcnt[i];
    if (c > SLOTS) c = SLOTS;

    if (t == 0) ndistinct = 0;
    for (int a = t; a < c; a += 256) {
        jcol[a] = rowj[i*SLOTS + a];
        dead[a] = 0;
        const float4* src = (const float4*)(rowv + ((size_t)i*SLOTS + a)*NP);
        float4* dst = (float4*)vals[a];
        dst[0] = src[0]; dst[1] = src[1]; dst[2] = src[2]; dst[3] = src[3];
    }
    __syncthreads();

    // merge duplicate columns into first occurrence
    for (int a = t; a < c; a += 256) {
        int j = jcol[a];
        int first = a;
        for (int b = 0; b < a; ++b) if (jcol[b] == j) { first = b; break; }
        if (first != a) {
            dead[a] = 1;
            #pragma unroll
            for (int p = 0; p < NP; ++p) atomicAdd(&vals[first][p], vals[a][p]);
        }
    }
    __syncthreads();
    for (int a = t; a < c; a += 256)
        if (!dead[a] && jcol[a] != i) atomicAdd(&ndistinct, 1);
    __syncthreads();

    // stats: 16 chunks x 16 p
    const int p = t & 15, ch = t >> 4;
    float pm = 0.f;   // background logit 0 always present
    for (int a = ch; a < c; a += 16)
        if (!dead[a] && jcol[a] != i) pm = fmaxf(pm, vals[a][p]);
    red[ch][p] = pm;
    __syncthreads();
    if (t < NP) {
        float m = 0.f;
        #pragma unroll
        for (int k = 0; k < 16; ++k) m = fmaxf(m, red[k][t]);
        mP[t] = m;
    }
    __syncthreads();
    {
        const float m = mP[p];
        float ps = 0.f;
        for (int a = ch; a < c; a += 16)
            if (!dead[a] && jcol[a] != i) ps += __expf(vals[a][p] - m);
        red[ch][p] = ps;
    }
    __syncthreads();
    if (t < NP) {
        float zs = 0.f;
        #pragma unroll
        for (int k = 0; k < 16; ++k) zs += red[k][t];
        const float m = mP[t];
        const float eb = __expf(-m);
        const float nbg = (float)(N_NODES - 1 - ndistinct);
        const float Z = zs + nbg * eb;
        const float iz = 1.0f / Z;
        invZ[t] = iz; bg[t] = eb * iz;
    }
    __syncthreads();

    // dense background write (non-temporal): 8192 float4
    const size_t rowbase = (size_t)i * N_NODES * NP;
    {
        const int g = t & 3;
        const float b0 = bg[g*4+0], b1 = bg[g*4+1], b2 = bg[g*4+2], b3 = bg[g*4+3];
        float* orow = out + rowbase;
        #pragma unroll 8
        for (int n = 0; n < 32; ++n)
            store_nt4(orow + 4*(t + 256*n), b0, b1, b2, b3);
    }
    __syncthreads();

    // fixups: sparse columns and diagonal
    for (int a = t; a < c; a += 256) {
        if (dead[a]) continue;
        const int j = jcol[a];
        float* dst = out + rowbase + (size_t)j * NP;
        if (j == i) {
            store_nt4(dst+0,  0.f,0.f,0.f,0.f);
            store_nt4(dst+4,  0.f,0.f,0.f,0.f);
            store_nt4(dst+8,  0.f,0.f,0.f,0.f);
            store_nt4(dst+12, 0.f,0.f,0.f,0.f);
        } else {
            #pragma unroll
            for (int q = 0; q < 4; ++q) {
                store_nt4(dst + 4*q,
                    __expf(vals[a][4*q+0] - mP[4*q+0]) * invZ[4*q+0],
                    __expf(vals[a][4*q+1] - mP[4*q+1]) * invZ[4*q+1],
                    __expf(vals[a][4*q+2] - mP[4*q+2]) * invZ[4*q+2],
                    __expf(vals[a][4*q+3] - mP[4*q+3]) * invZ[4*q+3]);
            }
        }
    }
    if (t == 0) {
        float* dst = out + rowbase + (size_t)i * NP;
        store_nt4(dst+0,  0.f,0.f,0.f,0.f);
        store_nt4(dst+4,  0.f,0.f,0.f,0.f);
        store_nt4(dst+8,  0.f,0.f,0.f,0.f);
        store_nt4(dst+12, 0.f,0.f,0.f,0.f);
    }
}

// ---------------------------------------------------------------------------
extern "C" void kernel_launch(void* const* d_in, const int* in_sizes, int n_in,
                              void* d_out, int out_size, void* d_ws, size_t ws_size,
                              hipStream_t stream)
{
    (void)in_sizes; (void)n_in; (void)out_size; (void)ws_size;
    const float* obj  = (const float*)d_in[0];
    const float* uni  = (const float*)d_in[1];
    const int*   idx  = (const int*)  d_in[2];
    const float* ws_w = (const float*)d_in[3];
    const float* ws_b = (const float*)d_in[4];
    const float* wo_w = (const float*)d_in[5];
    const float* wo_b = (const float*)d_in[6];
    const float* w_w  = (const float*)d_in[7];
    const float* w_b  = (const float*)d_in[8];
    float* out = (float*)d_out;

    unsigned short* Sb = (unsigned short*)d_ws;                     // 2 MB bf16
    unsigned short* Ob = Sb + (size_t)N_NODES * DIM;                // 2 MB bf16
    float* rowv  = (float*)(Ob + (size_t)N_NODES * DIM);            // 12.6 MB
    int* rowj    = (int*)(rowv + (size_t)N_NODES * SLOTS * NP);     // 768 KB
    int* rowcnt  = rowj + (size_t)N_NODES * SLOTS;                  // 8 KB

    gemm_so<<<dim3(1024/GBN, N_NODES/GBM), 256, 0, stream>>>(obj, ws_w, ws_b, wo_w, wo_b, Sb, Ob, rowcnt);
    pairproj_k<<<N_PAIRS/128, 256, 0, stream>>>(Sb, Ob, uni, idx, w_w, w_b, rowcnt, rowj, rowv);
    softmax_k<<<N_NODES, 256, 0, stream>>>(rowcnt, rowj, rowv, out);
}